// Round 8
// baseline (4591.978 us; speedup 1.0000x reference)
//
#include <hip/hip_runtime.h>
#include <cstdint>
#include <cstddef>

#define HID 256

typedef __bf16 bf16;
typedef __bf16 bf16x4 __attribute__((ext_vector_type(4)));
typedef __bf16 bf16x8 __attribute__((ext_vector_type(8)));
typedef float f32x4 __attribute__((ext_vector_type(4)));

// ---------------- CSR build ----------------

__global__ void k_zero_i32(int* __restrict__ p, int n) {
  int i = blockIdx.x * blockDim.x + threadIdx.x;
  if (i < n) p[i] = 0;
}

__global__ void k_hist(const int* __restrict__ ei, int* __restrict__ deg, int E) {
  int i = blockIdx.x * blockDim.x + threadIdx.x;
  if (i < E) atomicAdd(&deg[ei[E + i]], 1);  // dst = ei[E + i]
}

__global__ void k_scan1(const int* __restrict__ deg, int* __restrict__ offs,
                        int* __restrict__ bsums, int n) {
  __shared__ int sh[1024];
  int i = blockIdx.x * 1024 + threadIdx.x;
  int v = (i < n) ? deg[i] : 0;
  sh[threadIdx.x] = v;
  __syncthreads();
  for (int d = 1; d < 1024; d <<= 1) {
    int t = (threadIdx.x >= (unsigned)d) ? sh[threadIdx.x - d] : 0;
    __syncthreads();
    sh[threadIdx.x] += t;
    __syncthreads();
  }
  if (i < n) offs[i] = sh[threadIdx.x] - v;  // exclusive within block
  if (threadIdx.x == 1023) bsums[blockIdx.x] = sh[1023];
}

__global__ void k_scan2(int* __restrict__ bsums, int nb) {
  if (threadIdx.x == 0 && blockIdx.x == 0) {
    int run = 0;
    for (int b = 0; b < nb; ++b) { int t = bsums[b]; bsums[b] = run; run += t; }
  }
}

__global__ void k_scan3(int* __restrict__ offs, int* __restrict__ cursor,
                        const int* __restrict__ bsums, int n, int E) {
  int i = blockIdx.x * 1024 + threadIdx.x;
  if (i < n) { int o = offs[i] + bsums[blockIdx.x]; offs[i] = o; cursor[i] = o; }
  if (i == 0) offs[n] = E;
}

__global__ void k_fill(const int* __restrict__ ei, int* __restrict__ cursor,
                       int* __restrict__ csr, int E) {
  int i = blockIdx.x * blockDim.x + threadIdx.x;
  if (i < E) {
    int pos = atomicAdd(&cursor[ei[E + i]], 1);
    csr[pos] = ei[i];  // store src, keyed by dst
  }
}

// ---------------- fragment-pack weights ----------------
// P[mat][tile][kt][lane][8]: lane holds W[tile*16 + (lane&15)][kt*32 + (lane>>4)*8 + j]

__global__ void k_pack(const float* __restrict__ W, bf16* __restrict__ P,
                       int OUT, int K, int count) {
  int g = blockIdx.x * blockDim.x + threadIdx.x;
  int total = count * OUT * (K >> 3);
  if (g >= total) return;
  int lane = g & 63;
  int rest = g >> 6;
  int KT = K >> 5;
  int kt = rest % KT;
  int rest2 = rest / KT;
  int OT = OUT >> 4;
  int tile = rest2 % OT;
  int mat = rest2 / OT;
  const float* src = W + (size_t)mat * OUT * K +
                     (size_t)(tile * 16 + (lane & 15)) * K + kt * 32 + (lane >> 4) * 8;
  bf16* dst = P + (size_t)g * 8;
#pragma unroll
  for (int j = 0; j < 8; ++j) dst[j] = (bf16)src[j];
}

// ---------------- input fc (+ zero all per-layer sums slots and counters) ----------------

__global__ void k_input_fc(const float* __restrict__ x, const float* __restrict__ Win,
                           float* __restrict__ h, bf16* __restrict__ hb,
                           float* __restrict__ sums, int* __restrict__ ctr,
                           int L, int N) {
  int i = blockIdx.x;
  int c = threadIdx.x;
  if (i == 0) {
    for (int k = 0; k < L; ++k) {
      sums[k * 512 + c] = 0.f;
      sums[k * 512 + 256 + c] = 0.f;
    }
    if (c < L) ctr[c] = 0;
  }
  float v = x[2 * i] * Win[2 * c] + x[2 * i + 1] * Win[2 * c + 1];
  size_t idx = (size_t)i * HID + c;
  h[idx] = v;
  hb[idx] = (bf16)v;
}

// ---------------- aggregation: 2 nodes per wave, 4-deep gather ILP ----------------

__global__ __launch_bounds__(256) void k_aggregate(
    const bf16* __restrict__ hb, const int* __restrict__ offs,
    const int* __restrict__ csr, bf16* __restrict__ aggb, int N) {
  int gwave = (int)((blockIdx.x * blockDim.x + threadIdx.x) >> 6);
  int lane = threadIdx.x & 63;
  int node = gwave * 2 + (lane >> 5);
  int l32 = lane & 31;
  if (node >= N) return;
  int e0 = offs[node], e1 = offs[node + 1];
  float a[8] = {};
  int e = e0;
  for (; e + 3 < e1; e += 4) {  // 4 independent 16B gathers in flight
    int s0 = csr[e], s1 = csr[e + 1], s2 = csr[e + 2], s3 = csr[e + 3];
    bf16x8 v0 = *(const bf16x8*)(hb + (size_t)s0 * HID + l32 * 8);
    bf16x8 v1 = *(const bf16x8*)(hb + (size_t)s1 * HID + l32 * 8);
    bf16x8 v2 = *(const bf16x8*)(hb + (size_t)s2 * HID + l32 * 8);
    bf16x8 v3 = *(const bf16x8*)(hb + (size_t)s3 * HID + l32 * 8);
#pragma unroll
    for (int k = 0; k < 8; ++k)
      a[k] += ((float)v0[k] + (float)v1[k]) + ((float)v2[k] + (float)v3[k]);
  }
  for (; e < e1; ++e) {
    int s0 = csr[e];
    bf16x8 v0 = *(const bf16x8*)(hb + (size_t)s0 * HID + l32 * 8);
#pragma unroll
    for (int k = 0; k < 8; ++k) a[k] += (float)v0[k];
  }
  bf16x8 o;
#pragma unroll
  for (int k = 0; k < 8; ++k) o[k] = (bf16)a[k];
  *(bf16x8*)(aggb + (size_t)node * HID + l32 * 8) = o;
}

// ---------------- fused layer: GEMM + BN stats + grid-spin-sync + BN apply + residual ----
// Block = 64 nodes x 256 ch, operand-swapped MFMA D[ch][node]. Packed-LDS B staging
// (conflict-free both directions). After stats: device-scope counter sync (grid 782
// <= 1024 co-resident: LDS 34.8KB -> 4 blk/CU, launch_bounds(256,4) -> VGPR<=128),
// then BN+ReLU+residual applied straight from accumulator registers.
// outb and the separate bn kernel are gone.

__global__ __launch_bounds__(256, 4) void k_layer_fused(
    const bf16* __restrict__ aggb, const bf16* __restrict__ hb_r,
    const bf16* __restrict__ Pr, const bf16* __restrict__ Po,
    const float* __restrict__ bias, const float* __restrict__ gamma,
    const float* __restrict__ beta, float* __restrict__ h,
    bf16* __restrict__ hbw, float* __restrict__ sums, int* __restrict__ ctr,
    int nblk, int N, float invN) {
  __shared__ __align__(16) bf16 bt[32 * 64 * 8];  // 32KB packed [(kt*4+j)][lane][8]
  __shared__ float bsum[256], bsq[256];
  int tid = threadIdx.x;
  int wave = tid >> 6, lane = tid & 63;
  int l15 = lane & 15, lq = lane >> 4;
  int m0 = blockIdx.x * 64;
  f32x4 acc[4][4] = {};
  const bf16* PrW = Pr + (size_t)wave * 4 * 8 * 64 * 8;
  const bf16* PoW = Po + (size_t)wave * 4 * 8 * 64 * 8;
  int rr = tid & 63, cb = tid >> 6;  // staging: lane = row, wave = chunk-slot
  int sj = rr >> 4, sl = rr & 15;

  for (int phase = 0; phase < 2; ++phase) {
    const bf16* src = phase ? hb_r : aggb;
    if (phase) __syncthreads();
    {
      int gr = m0 + rr;
      bool ok = gr < N;
#pragma unroll
      for (int it = 0; it < 8; ++it) {
        int c = cb + it * 4;  // 16B chunk 0..31
        bf16x8 v = {};
        if (ok) v = *(const bf16x8*)(src + (size_t)gr * HID + c * 8);
        *(bf16x8*)(&bt[(((c >> 2) * 4 + sj) * 64 + (c & 3) * 16 + sl) * 8]) = v;
      }
    }
    __syncthreads();
    const bf16* PW = phase ? PoW : PrW;
    for (int kt = 0; kt < 8; ++kt) {
      bf16x8 bfr[4];
#pragma unroll
      for (int j = 0; j < 4; ++j)
        bfr[j] = *(const bf16x8*)(&bt[((kt * 4 + j) * 64 + lane) * 8]);
#pragma unroll
      for (int i = 0; i < 4; ++i) {
        bf16x8 afr = *(const bf16x8*)(PW + ((size_t)(i * 8 + kt) * 64 + lane) * 8);
#pragma unroll
        for (int j = 0; j < 4; ++j)
          acc[i][j] = __builtin_amdgcn_mfma_f32_16x16x32_bf16(afr, bfr[j], acc[i][j], 0, 0, 0);
      }
    }
  }

  // ---- bias add (in place) + BN stats ----
  f32x4 bv[4];
#pragma unroll
  for (int i = 0; i < 4; ++i)
    bv[i] = *(const f32x4*)(bias + wave * 64 + i * 16 + lq * 4);
  float s[4][4] = {}, q[4][4] = {};
#pragma unroll
  for (int j = 0; j < 4; ++j) {
    bool ok = (m0 + j * 16 + l15) < N;
#pragma unroll
    for (int i = 0; i < 4; ++i) {
#pragma unroll
      for (int r = 0; r < 4; ++r) {
        float v = acc[i][j][r] + bv[i][r];
        acc[i][j][r] = v;
        if (ok) { s[i][r] += v; q[i][r] += v * v; }
      }
    }
  }
#pragma unroll
  for (int d = 1; d < 16; d <<= 1) {
#pragma unroll
    for (int i = 0; i < 4; ++i)
#pragma unroll
      for (int r = 0; r < 4; ++r) {
        s[i][r] += __shfl_xor(s[i][r], d, 64);
        q[i][r] += __shfl_xor(q[i][r], d, 64);
      }
  }
  if (l15 == 0) {
#pragma unroll
    for (int i = 0; i < 4; ++i)
#pragma unroll
      for (int r = 0; r < 4; ++r) {
        bsum[wave * 64 + i * 16 + lq * 4 + r] = s[i][r];
        bsq[wave * 64 + i * 16 + lq * 4 + r] = q[i][r];
      }
  }
  __syncthreads();
  atomicAdd(&sums[tid], bsum[tid]);
  atomicAdd(&sums[256 + tid], bsq[tid]);

  // ---- grid-wide sync: device-scope counter ----
  __threadfence();
  __syncthreads();  // implies vmcnt(0): stats atomics issued & drained
  if (tid == 0) {
    atomicAdd(ctr, 1);
    long spin = 0;
    while (__hip_atomic_load(ctr, __ATOMIC_ACQUIRE, __HIP_MEMORY_SCOPE_AGENT) < nblk) {
      __builtin_amdgcn_s_sleep(8);
      if (++spin > (1L << 26)) break;  // safety fuse (~hang guard)
    }
  }
  __syncthreads();

  // ---- BN apply + ReLU + residual, straight from registers ----
  f32x4 av[4], bw[4];
#pragma unroll
  for (int i = 0; i < 4; ++i) {
#pragma unroll
    for (int r = 0; r < 4; ++r) {
      int ch = wave * 64 + i * 16 + lq * 4 + r;
      float mean = __hip_atomic_load(&sums[ch], __ATOMIC_RELAXED,
                                     __HIP_MEMORY_SCOPE_AGENT) * invN;
      float var = __hip_atomic_load(&sums[256 + ch], __ATOMIC_RELAXED,
                                    __HIP_MEMORY_SCOPE_AGENT) * invN - mean * mean;
      float istd = rsqrtf(var + 1e-5f);
      av[i][r] = istd * gamma[ch];
      bw[i][r] = fmaf(-mean, av[i][r], beta[ch]);
    }
  }
#pragma unroll
  for (int j = 0; j < 4; ++j) {
    int gn = m0 + j * 16 + l15;
    if (gn >= N) continue;
#pragma unroll
    for (int i = 0; i < 4; ++i) {
      size_t idx = (size_t)gn * HID + wave * 64 + i * 16 + lq * 4;
      float4 hv = *(const float4*)(h + idx);
      float hn[4];
      bf16x4 ob;
#pragma unroll
      for (int r = 0; r < 4; ++r) {
        float y = fmaf(acc[i][j][r], av[i][r], bw[i][r]);
        y = fmaxf(y, 0.f);
        hn[r] = ((const float*)&hv)[r] + y;
        ob[r] = (bf16)hn[r];
      }
      *(float4*)(h + idx) = make_float4(hn[0], hn[1], hn[2], hn[3]);
      *(bf16x4*)(hbw + idx) = ob;
    }
  }
}

// ---------------- fused edge MLP (per-ks staged; best-measured variant, 394us) -------
// 64 edges/block, 4 waves. GEMM1: B staged per-ks into packed LDS. z1 -> packed z1f.
// GEMM2 from z1f, z2 stays in registers.

__global__ __launch_bounds__(256) void k_edge_mlp(
    const bf16* __restrict__ hb, const int* __restrict__ eidx,
    const bf16* __restrict__ P1, const float* __restrict__ b1v,
    const bf16* __restrict__ P2, const float* __restrict__ b2v,
    const float* __restrict__ w3, const float* __restrict__ b3,
    float* __restrict__ outp, int E) {
  __shared__ __align__(16) bf16 asp[4 * 64 * 8];   // 4KB packed staging
  __shared__ __align__(16) bf16 z1f[32 * 64 * 8];  // 32KB packed z1
  __shared__ int nd[128];  // [0..63]=src, [64..127]=dst
  __shared__ float red[64];
  int tid = threadIdx.x;
  int e0 = blockIdx.x * 64;
  if (tid < 128) {
    int e = e0 + (tid & 63);
    nd[tid] = (e < E) ? eidx[(size_t)(tid >> 6) * E + e] : 0;
  }
  if (tid < 64) red[tid] = 0.f;
  __syncthreads();
  int wave = tid >> 6, lane = tid & 63;
  int l15 = lane & 15, lq = lane >> 4;
  int sr = tid >> 2, sq = tid & 3;

  // ---- GEMM1: D[c1][e] = W1 . cat^T, K=512 ----
  f32x4 acc[4][4] = {};
  const bf16* P1W = P1 + (size_t)wave * 4 * 16 * 64 * 8;
  for (int ks = 0; ks < 16; ++ks) {
    {
      int node = nd[(ks >> 3) * 64 + sr];
      bf16x8 v = *(const bf16x8*)(hb + (size_t)node * HID + (ks & 7) * 32 + sq * 8);
      *(bf16x8*)(&asp[((sr >> 4) * 64 + sq * 16 + (sr & 15)) * 8]) = v;
    }
    __syncthreads();
    bf16x8 bfr[4];
#pragma unroll
    for (int j = 0; j < 4; ++j)
      bfr[j] = *(const bf16x8*)(&asp[(j * 64 + lane) * 8]);  // lane-sequential
#pragma unroll
    for (int i = 0; i < 4; ++i) {
      bf16x8 wf = *(const bf16x8*)(P1W + ((size_t)(i * 16 + ks) * 64 + lane) * 8);
#pragma unroll
      for (int j = 0; j < 4; ++j)
        acc[i][j] = __builtin_amdgcn_mfma_f32_16x16x32_bf16(wf, bfr[j], acc[i][j], 0, 0, 0);
    }
    __syncthreads();
  }
  // z1 -> fragment-packed LDS (8B writes, benign 2-way alias)
  {
    f32x4 b1i[4];
#pragma unroll
    for (int i = 0; i < 4; ++i)
      b1i[i] = *(const f32x4*)(b1v + wave * 64 + i * 16 + lq * 4);
#pragma unroll
    for (int j = 0; j < 4; ++j) {
#pragma unroll
      for (int i = 0; i < 4; ++i) {
        bf16x4 o;
#pragma unroll
        for (int r = 0; r < 4; ++r)
          o[r] = (bf16)fmaxf(acc[i][j][r] + b1i[i][r], 0.f);
        int kt = wave * 2 + (i >> 1);
        int slot = l15 + 16 * ((i & 1) * 2 + (lq >> 1));
        *(bf16x4*)(&z1f[((j * 8 + kt) * 64 + slot) * 8 + (lq & 1) * 4]) = o;
      }
    }
  }
  __syncthreads();

  // ---- GEMM2: D[c2][e] = W2 . z1^T, K=256 ----
  f32x4 acc2[4][4] = {};
  const bf16* P2W = P2 + (size_t)wave * 4 * 8 * 64 * 8;
  for (int ks = 0; ks < 8; ++ks) {
    bf16x8 zf[4];
#pragma unroll
    for (int j = 0; j < 4; ++j)
      zf[j] = *(const bf16x8*)(&z1f[((j * 8 + ks) * 64 + lane) * 8]);
#pragma unroll
    for (int i = 0; i < 4; ++i) {
      bf16x8 wf = *(const bf16x8*)(P2W + ((size_t)(i * 8 + ks) * 64 + lane) * 8);
#pragma unroll
      for (int j = 0; j < 4; ++j)
        acc2[i][j] = __builtin_amdgcn_mfma_f32_16x16x32_bf16(wf, zf[j], acc2[i][j], 0, 0, 0);
    }
  }

  // ---- logit = relu(z2).w3 from registers; lane col = e ----
  f32x4 b2i[4], w3i[4];
#pragma unroll
  for (int i = 0; i < 4; ++i) {
    b2i[i] = *(const f32x4*)(b2v + wave * 64 + i * 16 + lq * 4);
    w3i[i] = *(const f32x4*)(w3 + wave * 64 + i * 16 + lq * 4);
  }
  float sj2[4] = {};
#pragma unroll
  for (int j = 0; j < 4; ++j)
#pragma unroll
    for (int i = 0; i < 4; ++i)
#pragma unroll
      for (int r = 0; r < 4; ++r)
        sj2[j] = fmaf(fmaxf(acc2[i][j][r] + b2i[i][r], 0.f), w3i[i][r], sj2[j]);
#pragma unroll
  for (int j = 0; j < 4; ++j) {
    sj2[j] += __shfl_xor(sj2[j], 16, 64);
    sj2[j] += __shfl_xor(sj2[j], 32, 64);
  }
  if (lq == 0) {
#pragma unroll
    for (int j = 0; j < 4; ++j)
      atomicAdd(&red[j * 16 + l15], sj2[j]);
  }
  __syncthreads();
  if (tid < 64) {
    int e = e0 + tid;
    if (e < E) {
      float logit = red[tid] + b3[0];
      outp[e] = 1.f / (1.f + expf(-logit));
    }
  }
}

// ---------------- host ----------------

static inline size_t align256(size_t x) { return (x + 255) & ~(size_t)255; }

extern "C" void kernel_launch(void* const* d_in, const int* in_sizes, int n_in,
                              void* d_out, int out_size, void* d_ws, size_t ws_size,
                              hipStream_t stream) {
  const float* x     = (const float*)d_in[0];
  const int*   ei    = (const int*)d_in[1];
  const float* Win   = (const float*)d_in[2];
  const float* Wrel  = (const float*)d_in[3];
  const float* brel  = (const float*)d_in[4];
  const float* Wroot = (const float*)d_in[5];
  const float* gamma = (const float*)d_in[6];
  const float* beta  = (const float*)d_in[7];
  const float* W1    = (const float*)d_in[8];
  const float* b1    = (const float*)d_in[9];
  const float* W2    = (const float*)d_in[10];
  const float* b2    = (const float*)d_in[11];
  const float* W3    = (const float*)d_in[12];
  const float* b3    = (const float*)d_in[13];

  const int N = in_sizes[0] / 2;              // 50000
  const int E = in_sizes[1] / 2;              // 500000
  const int L = in_sizes[3] / (HID * HID);    // 15

  char* p = (char*)d_ws;
  auto alloc = [&](size_t bytes) { char* r = p; p += align256(bytes); return r; };
  float* h     = (float*)alloc((size_t)N * HID * 4);
  bf16*  hb    = (bf16*)alloc((size_t)N * HID * 2);
  bf16*  aggb  = (bf16*)alloc((size_t)N * HID * 2);
  bf16*  Prel  = (bf16*)alloc((size_t)L * HID * HID * 2);
  bf16*  Proot = (bf16*)alloc((size_t)L * HID * HID * 2);
  bf16*  P1    = (bf16*)alloc((size_t)HID * 2 * HID * 2);
  bf16*  P2    = (bf16*)alloc((size_t)HID * HID * 2);
  int*   deg   = (int*)alloc((size_t)N * 4);
  int*   offs  = (int*)alloc((size_t)(N + 1) * 4);
  int*   cursor= (int*)alloc((size_t)N * 4);
  int*   csr   = (int*)alloc((size_t)E * 4);
  int*   bsums = (int*)alloc(64 * 4);
  float* sums  = (float*)alloc((size_t)L * 512 * 4);  // per-layer stats slots
  int*   ctr   = (int*)alloc((size_t)(L + 1) * 4);    // per-layer sync counters
  (void)ws_size; (void)n_in; (void)out_size;

  const int nb = (N + 1023) / 1024;

  // CSR build
  k_zero_i32<<<(N + 255) / 256, 256, 0, stream>>>(deg, N);
  k_hist<<<(E + 255) / 256, 256, 0, stream>>>(ei, deg, E);
  k_scan1<<<nb, 1024, 0, stream>>>(deg, offs, bsums, N);
  k_scan2<<<1, 64, 0, stream>>>(bsums, nb);
  k_scan3<<<nb, 1024, 0, stream>>>(offs, cursor, bsums, N, E);
  k_fill<<<(E + 255) / 256, 256, 0, stream>>>(ei, cursor, csr, E);

  // fragment-pack weights
  {
    int g1 = L * HID * HID / 8;
    k_pack<<<(g1 + 255) / 256, 256, 0, stream>>>(Wrel, Prel, HID, HID, L);
    k_pack<<<(g1 + 255) / 256, 256, 0, stream>>>(Wroot, Proot, HID, HID, L);
    int g2 = HID * 2 * HID / 8;
    k_pack<<<(g2 + 255) / 256, 256, 0, stream>>>(W1, P1, HID, 2 * HID, 1);
    int g3 = HID * HID / 8;
    k_pack<<<(g3 + 255) / 256, 256, 0, stream>>>(W2, P2, HID, HID, 1);
  }

  // input fc (+ zero per-layer sums/counters)
  k_input_fc<<<N, 256, 0, stream>>>(x, Win, h, hb, sums, ctr, L, N);

  // layers: aggregate -> fused gemm+BN+residual (grid-spin-synced)
  const float invN = 1.0f / (float)N;
  const int nblk = (N + 63) / 64;
  for (int l = 0; l < L; ++l) {
    k_aggregate<<<(N + 7) / 8, 256, 0, stream>>>(hb, offs, csr, aggb, N);
    k_layer_fused<<<nblk, 256, 0, stream>>>(
        aggb, hb, Prel + (size_t)l * HID * HID, Proot + (size_t)l * HID * HID,
        brel + (size_t)l * HID, gamma + (size_t)l * HID, beta + (size_t)l * HID,
        h, hb, sums + (size_t)l * 512, ctr + l, nblk, N, invN);
  }

  // edge MLP
  k_edge_mlp<<<(E + 63) / 64, 256, 0, stream>>>(
      hb, ei, P1, b1, P2, b2, W3, b3, (float*)d_out, E);
}

// Round 9
// 2008.118 us; speedup vs baseline: 2.2867x; 2.2867x over previous
//
#include <hip/hip_runtime.h>
#include <cstdint>
#include <cstddef>

#define HID 256

typedef __bf16 bf16;
typedef __bf16 bf16x4 __attribute__((ext_vector_type(4)));
typedef __bf16 bf16x8 __attribute__((ext_vector_type(8)));
typedef float f32x4 __attribute__((ext_vector_type(4)));

// ---------------- CSR build ----------------

__global__ void k_zero_i32(int* __restrict__ p, int n) {
  int i = blockIdx.x * blockDim.x + threadIdx.x;
  if (i < n) p[i] = 0;
}

__global__ void k_hist(const int* __restrict__ ei, int* __restrict__ deg, int E) {
  int i = blockIdx.x * blockDim.x + threadIdx.x;
  if (i < E) atomicAdd(&deg[ei[E + i]], 1);  // dst = ei[E + i]
}

__global__ void k_scan1(const int* __restrict__ deg, int* __restrict__ offs,
                        int* __restrict__ bsums, int n) {
  __shared__ int sh[1024];
  int i = blockIdx.x * 1024 + threadIdx.x;
  int v = (i < n) ? deg[i] : 0;
  sh[threadIdx.x] = v;
  __syncthreads();
  for (int d = 1; d < 1024; d <<= 1) {
    int t = (threadIdx.x >= (unsigned)d) ? sh[threadIdx.x - d] : 0;
    __syncthreads();
    sh[threadIdx.x] += t;
    __syncthreads();
  }
  if (i < n) offs[i] = sh[threadIdx.x] - v;  // exclusive within block
  if (threadIdx.x == 1023) bsums[blockIdx.x] = sh[1023];
}

__global__ void k_scan2(int* __restrict__ bsums, int nb) {
  if (threadIdx.x == 0 && blockIdx.x == 0) {
    int run = 0;
    for (int b = 0; b < nb; ++b) { int t = bsums[b]; bsums[b] = run; run += t; }
  }
}

__global__ void k_scan3(int* __restrict__ offs, int* __restrict__ cursor,
                        const int* __restrict__ bsums, int n, int E) {
  int i = blockIdx.x * 1024 + threadIdx.x;
  if (i < n) { int o = offs[i] + bsums[blockIdx.x]; offs[i] = o; cursor[i] = o; }
  if (i == 0) offs[n] = E;
}

__global__ void k_fill(const int* __restrict__ ei, int* __restrict__ cursor,
                       int* __restrict__ csr, int E) {
  int i = blockIdx.x * blockDim.x + threadIdx.x;
  if (i < E) {
    int pos = atomicAdd(&cursor[ei[E + i]], 1);
    csr[pos] = ei[i];  // store src, keyed by dst
  }
}

// ---------------- fragment-pack weights ----------------
// P[mat][tile][kt][lane][8]: lane holds W[tile*16 + (lane&15)][kt*32 + (lane>>4)*8 + j]

__global__ void k_pack(const float* __restrict__ W, bf16* __restrict__ P,
                       int OUT, int K, int count) {
  int g = blockIdx.x * blockDim.x + threadIdx.x;
  int total = count * OUT * (K >> 3);
  if (g >= total) return;
  int lane = g & 63;
  int rest = g >> 6;
  int KT = K >> 5;
  int kt = rest % KT;
  int rest2 = rest / KT;
  int OT = OUT >> 4;
  int tile = rest2 % OT;
  int mat = rest2 / OT;
  const float* src = W + (size_t)mat * OUT * K +
                     (size_t)(tile * 16 + (lane & 15)) * K + kt * 32 + (lane >> 4) * 8;
  bf16* dst = P + (size_t)g * 8;
#pragma unroll
  for (int j = 0; j < 8; ++j) dst[j] = (bf16)src[j];
}

// ---------------- input fc, grid-stride (+ zero sums buffer 0) ----------------

__global__ __launch_bounds__(256) void k_input_fc(
    const float* __restrict__ x, const float* __restrict__ Win,
    bf16* __restrict__ hb, float* __restrict__ sums0, int N) {
  int gid = blockIdx.x * blockDim.x + threadIdx.x;
  if (blockIdx.x == 0) { sums0[threadIdx.x] = 0.f; sums0[256 + threadIdx.x] = 0.f; }
  int total = N * HID;
  int stride = gridDim.x * blockDim.x;
  for (int idx = gid; idx < total; idx += stride) {
    int node = idx >> 8, c = idx & 255;
    float v = x[2 * node] * Win[2 * c] + x[2 * node + 1] * Win[2 * c + 1];
    hb[idx] = (bf16)v;
  }
}

// ---------------- aggregation: 2 nodes per wave, 4-deep gather ILP ----------------

__global__ __launch_bounds__(256) void k_aggregate(
    const bf16* __restrict__ hb, const int* __restrict__ offs,
    const int* __restrict__ csr, bf16* __restrict__ aggb, int N) {
  int gwave = (int)((blockIdx.x * blockDim.x + threadIdx.x) >> 6);
  int lane = threadIdx.x & 63;
  int node = gwave * 2 + (lane >> 5);
  int l32 = lane & 31;
  if (node >= N) return;
  int e0 = offs[node], e1 = offs[node + 1];
  float a[8] = {};
  int e = e0;
  for (; e + 3 < e1; e += 4) {  // 4 independent 16B gathers in flight
    int s0 = csr[e], s1 = csr[e + 1], s2 = csr[e + 2], s3 = csr[e + 3];
    bf16x8 v0 = *(const bf16x8*)(hb + (size_t)s0 * HID + l32 * 8);
    bf16x8 v1 = *(const bf16x8*)(hb + (size_t)s1 * HID + l32 * 8);
    bf16x8 v2 = *(const bf16x8*)(hb + (size_t)s2 * HID + l32 * 8);
    bf16x8 v3 = *(const bf16x8*)(hb + (size_t)s3 * HID + l32 * 8);
#pragma unroll
    for (int k = 0; k < 8; ++k)
      a[k] += ((float)v0[k] + (float)v1[k]) + ((float)v2[k] + (float)v3[k]);
  }
  for (; e < e1; ++e) {
    int s0 = csr[e];
    bf16x8 v0 = *(const bf16x8*)(hb + (size_t)s0 * HID + l32 * 8);
#pragma unroll
    for (int k = 0; k < 8; ++k) a[k] += (float)v0[k];
  }
  bf16x8 o;
#pragma unroll
  for (int k = 0; k < 8; ++k) o[k] = (bf16)a[k];
  *(bf16x8*)(aggb + (size_t)node * HID + l32 * 8) = o;
}

// ---------------- layer GEMM: out = agg@Wr^T + h@Wo^T + br, + BN stats ----------------
// Block = 64 nodes x 256 ch, operand-swapped MFMA D[ch][node].
// Packed-LDS B staging, conflict-free both directions; 3 barriers total.

__global__ __launch_bounds__(256) void k_layer_gemm(
    const bf16* __restrict__ aggb, const bf16* __restrict__ hb,
    const bf16* __restrict__ Pr, const bf16* __restrict__ Po,
    const float* __restrict__ bias, bf16* __restrict__ out,
    float* __restrict__ sums, int N) {
  __shared__ __align__(16) bf16 bt[32 * 64 * 8];  // 32KB packed [(kt*4+j)][lane][8]
  __shared__ float bsum[256], bsq[256];
  int tid = threadIdx.x;
  int wave = tid >> 6, lane = tid & 63;
  int l15 = lane & 15, lq = lane >> 4;
  int m0 = blockIdx.x * 64;
  f32x4 acc[4][4] = {};
  const bf16* PrW = Pr + (size_t)wave * 4 * 8 * 64 * 8;
  const bf16* PoW = Po + (size_t)wave * 4 * 8 * 64 * 8;
  int rr = tid & 63, cb = tid >> 6;  // staging: lane = row, wave = chunk-slot
  int sj = rr >> 4, sl = rr & 15;

  for (int phase = 0; phase < 2; ++phase) {
    const bf16* src = phase ? hb : aggb;
    if (phase) __syncthreads();  // previous consume done before overwrite
    {
      int gr = m0 + rr;
      bool ok = gr < N;
#pragma unroll
      for (int it = 0; it < 8; ++it) {
        int c = cb + it * 4;               // 16B chunk 0..31
        bf16x8 v = {};
        if (ok) v = *(const bf16x8*)(src + (size_t)gr * HID + c * 8);
        *(bf16x8*)(&bt[(((c >> 2) * 4 + sj) * 64 + (c & 3) * 16 + sl) * 8]) = v;
      }
    }
    __syncthreads();
    const bf16* PW = phase ? PoW : PrW;
    for (int kt = 0; kt < 8; ++kt) {
      bf16x8 bfr[4];
#pragma unroll
      for (int j = 0; j < 4; ++j)
        bfr[j] = *(const bf16x8*)(&bt[((kt * 4 + j) * 64 + lane) * 8]);
#pragma unroll
      for (int i = 0; i < 4; ++i) {
        bf16x8 afr = *(const bf16x8*)(PW + ((size_t)(i * 8 + kt) * 64 + lane) * 8);
#pragma unroll
        for (int j = 0; j < 4; ++j)
          acc[i][j] = __builtin_amdgcn_mfma_f32_16x16x32_bf16(afr, bfr[j], acc[i][j], 0, 0, 0);
      }
    }
  }

  // epilogue: bias, 8B stores, BN stats (in-lane j-sum + l15 butterfly)
  f32x4 bv[4];
#pragma unroll
  for (int i = 0; i < 4; ++i)
    bv[i] = *(const f32x4*)(bias + wave * 64 + i * 16 + lq * 4);
  float s[4][4] = {}, q[4][4] = {};
#pragma unroll
  for (int j = 0; j < 4; ++j) {
    int gn = m0 + j * 16 + l15;
    bool ok = gn < N;
#pragma unroll
    for (int i = 0; i < 4; ++i) {
      bf16x4 o;
#pragma unroll
      for (int r = 0; r < 4; ++r) {
        float v = acc[i][j][r] + bv[i][r];
        o[r] = (bf16)v;
        if (ok) { s[i][r] += v; q[i][r] += v * v; }
      }
      if (ok) *(bf16x4*)(out + (size_t)gn * HID + wave * 64 + i * 16 + lq * 4) = o;
    }
  }
#pragma unroll
  for (int d = 1; d < 16; d <<= 1) {
#pragma unroll
    for (int i = 0; i < 4; ++i)
#pragma unroll
      for (int r = 0; r < 4; ++r) {
        s[i][r] += __shfl_xor(s[i][r], d, 64);
        q[i][r] += __shfl_xor(q[i][r], d, 64);
      }
  }
  if (l15 == 0) {
#pragma unroll
    for (int i = 0; i < 4; ++i)
#pragma unroll
      for (int r = 0; r < 4; ++r) {
        bsum[wave * 64 + i * 16 + lq * 4 + r] = s[i][r];
        bsq[wave * 64 + i * 16 + lq * 4 + r] = q[i][r];
      }
  }
  __syncthreads();
  atomicAdd(&sums[tid], bsum[tid]);
  atomicAdd(&sums[256 + tid], bsq[tid]);
}

// ---------------- BN finalize + ReLU + residual (h kept in bf16, in place) ----------------
// hb_new = bf16( (float)hb_old + relu(bn(outb)) ). 77MB/layer instead of 154MB.

__global__ __launch_bounds__(256) void k_bn_residual(
    const bf16* __restrict__ outb, bf16* __restrict__ hb,
    const float* __restrict__ sums, float* __restrict__ zsums,
    const float* __restrict__ gamma, const float* __restrict__ beta,
    int N, float invN) {
  int t = threadIdx.x;
  if (blockIdx.x == 0) { zsums[t] = 0.f; zsums[256 + t] = 0.f; }
  int cg = (t & 31) * 8;
  int r0 = blockIdx.x * 32 + (t >> 5) * 4;
  float a[8], b[8];
#pragma unroll
  for (int k = 0; k < 8; ++k) {
    int c = cg + k;
    float mean = sums[c] * invN;
    float var = sums[256 + c] * invN - mean * mean;
    float istd = rsqrtf(var + 1e-5f);
    a[k] = istd * gamma[c];
    b[k] = fmaf(-mean, a[k], beta[c]);
  }
  int r1 = min(r0 + 4, N);
  for (int r = r0; r < r1; ++r) {
    size_t idx = (size_t)r * HID + cg;
    bf16x8 ov = *(const bf16x8*)(outb + idx);
    bf16x8 hv = *(const bf16x8*)(hb + idx);
    bf16x8 o;
#pragma unroll
    for (int k = 0; k < 8; ++k) {
      float y = fmaf((float)ov[k], a[k], b[k]);
      y = fmaxf(y, 0.f);
      o[k] = (bf16)((float)hv[k] + y);
    }
    *(bf16x8*)(hb + idx) = o;
  }
}

// ---------------- fused edge MLP (per-ks staged; best-measured variant) -------
// 64 edges/block, 4 waves. GEMM1: B staged per-ks into packed LDS. z1 -> packed z1f.
// GEMM2 from z1f, z2 stays in registers.

__global__ __launch_bounds__(256) void k_edge_mlp(
    const bf16* __restrict__ hb, const int* __restrict__ eidx,
    const bf16* __restrict__ P1, const float* __restrict__ b1v,
    const bf16* __restrict__ P2, const float* __restrict__ b2v,
    const float* __restrict__ w3, const float* __restrict__ b3,
    float* __restrict__ outp, int E) {
  __shared__ __align__(16) bf16 asp[4 * 64 * 8];   // 4KB packed staging
  __shared__ __align__(16) bf16 z1f[32 * 64 * 8];  // 32KB packed z1
  __shared__ int nd[128];  // [0..63]=src, [64..127]=dst
  __shared__ float red[64];
  int tid = threadIdx.x;
  int e0 = blockIdx.x * 64;
  if (tid < 128) {
    int e = e0 + (tid & 63);
    nd[tid] = (e < E) ? eidx[(size_t)(tid >> 6) * E + e] : 0;
  }
  if (tid < 64) red[tid] = 0.f;
  __syncthreads();
  int wave = tid >> 6, lane = tid & 63;
  int l15 = lane & 15, lq = lane >> 4;
  int sr = tid >> 2, sq = tid & 3;

  // ---- GEMM1: D[c1][e] = W1 . cat^T, K=512 ----
  f32x4 acc[4][4] = {};
  const bf16* P1W = P1 + (size_t)wave * 4 * 16 * 64 * 8;
  for (int ks = 0; ks < 16; ++ks) {
    {
      int node = nd[(ks >> 3) * 64 + sr];
      bf16x8 v = *(const bf16x8*)(hb + (size_t)node * HID + (ks & 7) * 32 + sq * 8);
      *(bf16x8*)(&asp[((sr >> 4) * 64 + sq * 16 + (sr & 15)) * 8]) = v;
    }
    __syncthreads();
    bf16x8 bfr[4];
#pragma unroll
    for (int j = 0; j < 4; ++j)
      bfr[j] = *(const bf16x8*)(&asp[(j * 64 + lane) * 8]);  // lane-sequential
#pragma unroll
    for (int i = 0; i < 4; ++i) {
      bf16x8 wf = *(const bf16x8*)(P1W + ((size_t)(i * 16 + ks) * 64 + lane) * 8);
#pragma unroll
      for (int j = 0; j < 4; ++j)
        acc[i][j] = __builtin_amdgcn_mfma_f32_16x16x32_bf16(wf, bfr[j], acc[i][j], 0, 0, 0);
    }
    __syncthreads();
  }
  // z1 -> fragment-packed LDS (8B writes, benign 2-way alias)
  {
    f32x4 b1i[4];
#pragma unroll
    for (int i = 0; i < 4; ++i)
      b1i[i] = *(const f32x4*)(b1v + wave * 64 + i * 16 + lq * 4);
#pragma unroll
    for (int j = 0; j < 4; ++j) {
#pragma unroll
      for (int i = 0; i < 4; ++i) {
        bf16x4 o;
#pragma unroll
        for (int r = 0; r < 4; ++r)
          o[r] = (bf16)fmaxf(acc[i][j][r] + b1i[i][r], 0.f);
        int kt = wave * 2 + (i >> 1);
        int slot = l15 + 16 * ((i & 1) * 2 + (lq >> 1));
        *(bf16x4*)(&z1f[((j * 8 + kt) * 64 + slot) * 8 + (lq & 1) * 4]) = o;
      }
    }
  }
  __syncthreads();

  // ---- GEMM2: D[c2][e] = W2 . z1^T, K=256 ----
  f32x4 acc2[4][4] = {};
  const bf16* P2W = P2 + (size_t)wave * 4 * 8 * 64 * 8;
  for (int ks = 0; ks < 8; ++ks) {
    bf16x8 zf[4];
#pragma unroll
    for (int j = 0; j < 4; ++j)
      zf[j] = *(const bf16x8*)(&z1f[((j * 8 + ks) * 64 + lane) * 8]);
#pragma unroll
    for (int i = 0; i < 4; ++i) {
      bf16x8 wf = *(const bf16x8*)(P2W + ((size_t)(i * 8 + ks) * 64 + lane) * 8);
#pragma unroll
      for (int j = 0; j < 4; ++j)
        acc2[i][j] = __builtin_amdgcn_mfma_f32_16x16x32_bf16(wf, zf[j], acc2[i][j], 0, 0, 0);
    }
  }

  // ---- logit = relu(z2).w3 from registers; lane col = e ----
  f32x4 b2i[4], w3i[4];
#pragma unroll
  for (int i = 0; i < 4; ++i) {
    b2i[i] = *(const f32x4*)(b2v + wave * 64 + i * 16 + lq * 4);
    w3i[i] = *(const f32x4*)(w3 + wave * 64 + i * 16 + lq * 4);
  }
  float sj2[4] = {};
#pragma unroll
  for (int j = 0; j < 4; ++j)
#pragma unroll
    for (int i = 0; i < 4; ++i)
#pragma unroll
      for (int r = 0; r < 4; ++r)
        sj2[j] = fmaf(fmaxf(acc2[i][j][r] + b2i[i][r], 0.f), w3i[i][r], sj2[j]);
#pragma unroll
  for (int j = 0; j < 4; ++j) {
    sj2[j] += __shfl_xor(sj2[j], 16, 64);
    sj2[j] += __shfl_xor(sj2[j], 32, 64);
  }
  if (lq == 0) {
#pragma unroll
    for (int j = 0; j < 4; ++j)
      atomicAdd(&red[j * 16 + l15], sj2[j]);
  }
  __syncthreads();
  if (tid < 64) {
    int e = e0 + tid;
    if (e < E) {
      float logit = red[tid] + b3[0];
      outp[e] = 1.f / (1.f + expf(-logit));
    }
  }
}

// ---------------- host ----------------

static inline size_t align256(size_t x) { return (x + 255) & ~(size_t)255; }

extern "C" void kernel_launch(void* const* d_in, const int* in_sizes, int n_in,
                              void* d_out, int out_size, void* d_ws, size_t ws_size,
                              hipStream_t stream) {
  const float* x     = (const float*)d_in[0];
  const int*   ei    = (const int*)d_in[1];
  const float* Win   = (const float*)d_in[2];
  const float* Wrel  = (const float*)d_in[3];
  const float* brel  = (const float*)d_in[4];
  const float* Wroot = (const float*)d_in[5];
  const float* gamma = (const float*)d_in[6];
  const float* beta  = (const float*)d_in[7];
  const float* W1    = (const float*)d_in[8];
  const float* b1    = (const float*)d_in[9];
  const float* W2    = (const float*)d_in[10];
  const float* b2    = (const float*)d_in[11];
  const float* W3    = (const float*)d_in[12];
  const float* b3    = (const float*)d_in[13];

  const int N = in_sizes[0] / 2;              // 50000
  const int E = in_sizes[1] / 2;              // 500000
  const int L = in_sizes[3] / (HID * HID);    // 15

  char* p = (char*)d_ws;
  auto alloc = [&](size_t bytes) { char* r = p; p += align256(bytes); return r; };
  bf16*  hb    = (bf16*)alloc((size_t)N * HID * 2);
  bf16*  outb  = (bf16*)alloc((size_t)N * HID * 2);
  bf16*  aggb  = (bf16*)alloc((size_t)N * HID * 2);
  bf16*  Prel  = (bf16*)alloc((size_t)L * HID * HID * 2);
  bf16*  Proot = (bf16*)alloc((size_t)L * HID * HID * 2);
  bf16*  P1    = (bf16*)alloc((size_t)HID * 2 * HID * 2);
  bf16*  P2    = (bf16*)alloc((size_t)HID * HID * 2);
  int*   deg   = (int*)alloc((size_t)N * 4);
  int*   offs  = (int*)alloc((size_t)(N + 1) * 4);
  int*   cursor= (int*)alloc((size_t)N * 4);
  int*   csr   = (int*)alloc((size_t)E * 4);
  int*   bsums = (int*)alloc(64 * 4);
  float* sums  = (float*)alloc(1024 * 4);  // two ping-pong buffers of 512
  (void)ws_size; (void)n_in; (void)out_size;

  const int nb = (N + 1023) / 1024;

  // CSR build
  k_zero_i32<<<(N + 255) / 256, 256, 0, stream>>>(deg, N);
  k_hist<<<(E + 255) / 256, 256, 0, stream>>>(ei, deg, E);
  k_scan1<<<nb, 1024, 0, stream>>>(deg, offs, bsums, N);
  k_scan2<<<1, 64, 0, stream>>>(bsums, nb);
  k_scan3<<<nb, 1024, 0, stream>>>(offs, cursor, bsums, N, E);
  k_fill<<<(E + 255) / 256, 256, 0, stream>>>(ei, cursor, csr, E);

  // fragment-pack weights
  {
    int g1 = L * HID * HID / 8;
    k_pack<<<(g1 + 255) / 256, 256, 0, stream>>>(Wrel, Prel, HID, HID, L);
    k_pack<<<(g1 + 255) / 256, 256, 0, stream>>>(Wroot, Proot, HID, HID, L);
    int g2 = HID * 2 * HID / 8;
    k_pack<<<(g2 + 255) / 256, 256, 0, stream>>>(W1, P1, HID, 2 * HID, 1);
    int g3 = HID * HID / 8;
    k_pack<<<(g3 + 255) / 256, 256, 0, stream>>>(W2, P2, HID, HID, 1);
  }

  // input fc (+ zero sums buffer 0)
  k_input_fc<<<1024, 256, 0, stream>>>(x, Win, hb, sums, N);

  // layers: aggregate -> GEMM(+stats) -> BN+ReLU+residual
  const float invN = 1.0f / (float)N;
  for (int l = 0; l < L; ++l) {
    int sel = l & 1;
    k_aggregate<<<(N + 7) / 8, 256, 0, stream>>>(hb, offs, csr, aggb, N);
    k_layer_gemm<<<(N + 63) / 64, 256, 0, stream>>>(
        aggb, hb, Prel + (size_t)l * HID * HID, Proot + (size_t)l * HID * HID,
        brel + (size_t)l * HID, outb, sums + sel * 512, N);
    k_bn_residual<<<(N + 31) / 32, 256, 0, stream>>>(
        outb, hb, sums + sel * 512, sums + (1 - sel) * 512,
        gamma + (size_t)l * HID, beta + (size_t)l * HID, N, invN);
  }

  // edge MLP
  k_edge_mlp<<<(E + 63) / 64, 256, 0, stream>>>(
      hb, ei, P1, b1, P2, b2, W3, b3, (float*)d_out, E);
}